// Round 17
// baseline (125.758 us; speedup 1.0000x reference)
//
#include <hip/hip_runtime.h>
#include <hip/hip_bf16.h>
#include <math.h>

#define H 128
#define TT 64
#define TWO_H 256
#define NGX 128
#define NACC 128
#define NTOT 512

typedef short short8 __attribute__((ext_vector_type(8)));
typedef __bf16 bf16x8_t __attribute__((ext_vector_type(8)));
typedef float f32x4 __attribute__((ext_vector_type(4)));
typedef unsigned int uint;

__device__ inline unsigned short bf_rne(float f) {
    __hip_bfloat16 b = __float2bfloat16(f);
    return __builtin_bit_cast(unsigned short, b);
}
__device__ inline void split_rne(float f, unsigned short& hi, unsigned short& lo) {
    __hip_bfloat16 h1 = __float2bfloat16(f);
    float fh = __bfloat162float(h1);
    hi = __builtin_bit_cast(unsigned short, h1);
    lo = bf_rne(f - fh);
}
__device__ inline f32x4 mfma_bf16(short8 a, short8 b, f32x4 c) {
    return __builtin_amdgcn_mfma_f32_16x16x32_bf16(
        __builtin_bit_cast(bf16x8_t, a), __builtin_bit_cast(bf16x8_t, b), c, 0, 0, 0);
}
__device__ inline float sigf(float x) { return 1.f / (1.f + __expf(-x)); }

// ---------- fallback (only if workspace too small for histogram path) ----------
__global__ void k_edges_fb(const float* __restrict__ nodes, const int* __restrict__ src,
                           const int* __restrict__ rel, const int* __restrict__ dst,
                           float* __restrict__ Sg, float* __restrict__ cntg, int E, int epb) {
    __shared__ float Sl[8 * 512];
    __shared__ float cnt[8];
    int t = threadIdx.x;
    for (int i = t; i < 8 * 512; i += 256) Sl[i] = 0.f;
    if (t < 8) cnt[t] = 0.f;
    __syncthreads();
    int e0 = blockIdx.x * epb, e1 = min(E, e0 + epb);
    int tS = ((t >> 7) << 8) + (t & 127);
    for (int e = e0; e < e1; ++e) {
        int r = rel[e];
        float vs = nodes[(size_t)src[e] * 256 + t];
        float vd = nodes[(size_t)dst[e] * 256 + t];
        Sl[r * 512 + tS] += vs;
        Sl[r * 512 + tS + 128] += vd;
        if (t == 0) cnt[r] += 1.f;
    }
    __syncthreads();
    for (int i = t; i < 8 * 512; i += 256) atomicAdd(&Sg[i], Sl[i]);
    if (t < 8) atomicAdd(&cntg[t], cnt[t]);
}

// ===== fused kernel (512 thr): GRU(b0)|GRU(b1) | combine | gx(+count) | accum | burn =====
// flags: [0]=accum, [1]=combine, [2]=count, [5]=gx done, [16]=GRU done (cold cacheline)
__launch_bounds__(512, 1)
__global__ void k_fused(const float* __restrict__ nodes, const int* __restrict__ src,
                        const int* __restrict__ rel, const int* __restrict__ dst,
                        const float* __restrict__ x, const float* __restrict__ Wih,
                        const float* __restrict__ bih, uint* __restrict__ csd,
                        float* __restrict__ Sg, float* __restrict__ cntg,
                        const float* __restrict__ relW, const float* __restrict__ relb,
                        float* __restrict__ gs, int* __restrict__ flags, float invE,
                        float* __restrict__ gxT2, const float* __restrict__ Whh,
                        const float* __restrict__ bhh, const float* __restrict__ W1,
                        const float* __restrict__ b1, const float* __restrict__ lng,
                        const float* __restrict__ lnb, const float* __restrict__ W2,
                        const float* __restrict__ b2v, float* __restrict__ out,
                        int N, int E, int nch, int naccum, int hist, int nreal) {
    int t = threadIdx.x;
    int bid = blockIdx.x;

    if (bid >= nreal) {
        // ===== burn v2: dependent-FMA spin (minimal issue), cold-line volatile poll =====
        float xx = (float)(t + 1) * 1e-8f;
        const volatile int* done = (const volatile int*)(flags + 16);
        while (*done < 2) {
#pragma unroll 8
            for (int i = 0; i < 512; ++i) xx = __builtin_fmaf(xx, 1.0000001f, 1e-9f);
        }
        asm volatile("" ::"v"(xx));
        return;
    }

    if (bid >= 10 && bid < 10 + NGX) {
        // ================= gx block: gx FIRST (signal), then count slice =================
        int idx = bid - 10;
        __shared__ float xs[H];
        int tt = idx >> 1, bb = idx & 1;
        if (t < H) xs[t] = x[(bb * TT + tt) * H + t];
        __syncthreads();
        for (int o = t; o < 384; o += 512) {
            const float4* wp = (const float4*)(Wih + o * H);
            float acc = 0.f;
#pragma unroll
            for (int i = 0; i < 32; ++i) {
                float4 w = wp[i];
                acc += w.x * xs[4 * i] + w.y * xs[4 * i + 1] + w.z * xs[4 * i + 2] +
                       w.w * xs[4 * i + 3];
            }
            float bias = bih[o] + (o < TWO_H ? bhh[o] : 0.f);  // bhh_n not foldable
            int g = o >> 7, j = o & 127;
            gxT2[((size_t)(bb * TT + tt) * 128 + j) * 4 + g] = acc + bias;  // [b][t][j][4]
        }
        __syncthreads();
        if (t == 0) {
            __threadfence();
            atomicAdd(&flags[5], 1);  // gx ready
        }
        if (hist) {
            int per = (E + NGX - 1) / NGX;
            int e0 = idx * per, e1 = min(E, e0 + per);
            for (int e = e0 + t; e < e1; e += 512) {
                int r = rel[e];
                atomicAdd(&csd[(size_t)src[e] * 8 + r], 1u);
                atomicAdd(&csd[(size_t)dst[e] * 8 + r], 65536u);
            }
            __syncthreads();
            if (t == 0) {
                __threadfence();
                atomicAdd(&flags[2], 1);
            }
        }
        return;
    }

    if (bid >= 10 + NGX) {
        // ================= accum: stream nodes once, weighted by counts =================
        int ai = bid - 10 - NGX;
        if (t == 0) {
            while (atomicAdd(&flags[2], 0) < NGX) __builtin_amdgcn_s_sleep(8);
            __threadfence();
        }
        __syncthreads();
        if (t < 256) {
            int n0 = ai * nch, n1 = min(N, n0 + nch);
            float sA[8] = {0, 0, 0, 0, 0, 0, 0, 0};
            float sB[8] = {0, 0, 0, 0, 0, 0, 0, 0};
            float caR[8] = {0, 0, 0, 0, 0, 0, 0, 0};
            int n = n0;
            for (; n + 4 <= n1; n += 4) {
                float v0 = nodes[(size_t)(n + 0) * 256 + t];
                float v1 = nodes[(size_t)(n + 1) * 256 + t];
                float v2 = nodes[(size_t)(n + 2) * 256 + t];
                float v3 = nodes[(size_t)(n + 3) * 256 + t];
                uint4 a0 = *(const uint4*)(csd + (size_t)(n + 0) * 8);
                uint4 a1 = *(const uint4*)(csd + (size_t)(n + 0) * 8 + 4);
                uint4 b0 = *(const uint4*)(csd + (size_t)(n + 1) * 8);
                uint4 b1u = *(const uint4*)(csd + (size_t)(n + 1) * 8 + 4);
                uint4 c0 = *(const uint4*)(csd + (size_t)(n + 2) * 8);
                uint4 c1 = *(const uint4*)(csd + (size_t)(n + 2) * 8 + 4);
                uint4 d0 = *(const uint4*)(csd + (size_t)(n + 3) * 8);
                uint4 d1 = *(const uint4*)(csd + (size_t)(n + 3) * 8 + 4);
                uint ca[8] = {a0.x, a0.y, a0.z, a0.w, a1.x, a1.y, a1.z, a1.w};
                uint cb[8] = {b0.x, b0.y, b0.z, b0.w, b1u.x, b1u.y, b1u.z, b1u.w};
                uint cc[8] = {c0.x, c0.y, c0.z, c0.w, c1.x, c1.y, c1.z, c1.w};
                uint cd2[8] = {d0.x, d0.y, d0.z, d0.w, d1.x, d1.y, d1.z, d1.w};
#pragma unroll
                for (int r = 0; r < 8; ++r) {
                    float fs0 = (float)(ca[r] & 0xffffu), fd0 = (float)(ca[r] >> 16);
                    float fs1 = (float)(cb[r] & 0xffffu), fd1 = (float)(cb[r] >> 16);
                    float fs2 = (float)(cc[r] & 0xffffu), fd2 = (float)(cc[r] >> 16);
                    float fs3 = (float)(cd2[r] & 0xffffu), fd3 = (float)(cd2[r] >> 16);
                    sA[r] += fs0 * v0 + fs1 * v1 + fs2 * v2 + fs3 * v3;
                    sB[r] += fd0 * v0 + fd1 * v1 + fd2 * v2 + fd3 * v3;
                    caR[r] += fs0 + fs1 + fs2 + fs3;
                }
            }
            for (; n < n1; ++n) {
                float v = nodes[(size_t)n * 256 + t];
                const uint* cp = csd + (size_t)n * 8;
                uint4 c0 = *(const uint4*)cp;
                uint4 c1 = *(const uint4*)(cp + 4);
                uint cc[8] = {c0.x, c0.y, c0.z, c0.w, c1.x, c1.y, c1.z, c1.w};
#pragma unroll
                for (int r = 0; r < 8; ++r) {
                    float fs = (float)(cc[r] & 0xffffu);
                    float fd = (float)(cc[r] >> 16);
                    sA[r] += fs * v;
                    sB[r] += fd * v;
                    caR[r] += fs;
                }
            }
            int b = t >> 7, h = t & 127;
#pragma unroll
            for (int r = 0; r < 8; ++r) {
                atomicAdd(&Sg[r * 512 + b * 256 + h], sA[r]);
                atomicAdd(&Sg[r * 512 + b * 256 + 128 + h], sB[r]);
            }
            if (t == 0) {
#pragma unroll
                for (int r = 0; r < 8; ++r) atomicAdd(&cntg[r], caR[r]);
            }
        }
        __syncthreads();
        if (t == 0) {
            __threadfence();
            atomicAdd(&flags[0], 1);
        }
        return;
    }

    if (bid >= 2) {
        // ================= combine r: gs += (S_r @ W_r + cnt_r*b_r)/E =================
        int r = bid - 2;
        __shared__ float Sc[512];
        if (t == 0) {
            while (atomicAdd(&flags[0], 0) < naccum) __builtin_amdgcn_s_sleep(8);
        }
        __syncthreads();
        for (int i = t; i < 512; i += 512) Sc[i] = atomicAdd(&Sg[r * 512 + i], 0.f);
        __syncthreads();
        if (t < 256) {
            int b = t >> 7, h = t & 127;
            const float* Wr = relW + (size_t)r * TWO_H * H;
            float acc = 0.f;
#pragma unroll 8
            for (int c = 0; c < TWO_H; ++c) acc += Sc[b * 256 + c] * Wr[c * H + h];
            acc += atomicAdd(&cntg[r], 0.f) * relb[r * H + h];
            atomicAdd(&gs[t], acc * invE);
        }
        __syncthreads();
        if (t == 0) {
            __threadfence();
            atomicAdd(&flags[1], 1);
        }
        return;
    }

    // ============ blocks 0,1: per-batch GRU, 8 waves, LDS-staged gx ============
    int b = bid;  // batch index
    __shared__ __align__(16) unsigned short h2[2][3][144];  // hi/lo/zero, dbuf
    __shared__ __align__(16) float gxs[2][8][128][4];       // 2 x 16KB staged gx chunks
    __shared__ float hfl[H];
    __shared__ float gl2[H];
    __shared__ float yl[TWO_H];
    __shared__ float red[16];

    int w = t >> 6, l = t & 63;  // 8 waves

    for (int i = t; i < 2 * 3 * 144; i += 512) ((unsigned short*)h2)[i] = 0;

    // B fragments: wave w owns j in [16w, 16w+16) for all 3 gates: tile g -> row-tile g*8+w
    short8 Bf[3][4];
#pragma unroll
    for (int g3 = 0; g3 < 3; ++g3) {
        int row = (g3 * 8 + w) * 16 + (l & 15);
#pragma unroll
        for (int kt = 0; kt < 4; ++kt) {
            const float4* wp = (const float4*)(Whh + row * H + kt * 32 + (l >> 4) * 8);
            float4 w0 = wp[0], w1 = wp[1];
            float ww[8] = {w0.x, w0.y, w0.z, w0.w, w1.x, w1.y, w1.z, w1.w};
            short8 v8;
#pragma unroll
            for (int e = 0; e < 8; ++e) v8[e] = (short)bf_rne(ww[e]);
            Bf[g3][kt] = v8;
        }
    }

    int al = l & 15;
    int rr = al < 2 ? al : 2;  // A-row: 0=hi 1=lo, >=2 zero broadcast
    int kg = (l >> 4) * 8;

    // gate lanes l<16: ONE unit each, j = w*16 + l
    float hp = 0.f;
    float bhn = 0.f;
    int j0 = w * 16 + l;
    if (l < 16) bhn = bhh[TWO_H + j0];

    const float* gxb = gxT2 + (size_t)b * TT * 512;  // this batch's gx [64][128][4]

    // wait once for ALL gx producers, then stage chunk 0 (16KB, 2 loads/wave)
    if (t == 0) {
        while (atomicAdd(&flags[5], 0) < NGX) __builtin_amdgcn_s_sleep(2);
        __threadfence();
    }
    __syncthreads();
    {
        float* lb = &gxs[0][0][0][0];
#pragma unroll
        for (int i = 0; i < 2; ++i) {
            __builtin_amdgcn_global_load_lds(
                (const __attribute__((address_space(1))) uint*)(gxb + w * 512 + i * 256 + l * 4),
                (__attribute__((address_space(3))) uint*)(lb + w * 512 + i * 256),
                16, 0, 0);
        }
    }
    __syncthreads();  // drains vmcnt(0): chunk 0 staged; h2 zeros visible

    __builtin_amdgcn_s_setprio(1);
    for (int c = 0; c < 8; ++c) {
        if (c < 7) {
            float* lb = &gxs[(c + 1) & 1][0][0][0];
            const float* sb = gxb + (size_t)(c + 1) * 4096;
#pragma unroll
            for (int i = 0; i < 2; ++i) {
                __builtin_amdgcn_global_load_lds(
                    (const __attribute__((address_space(1))) uint*)(sb + w * 512 + i * 256 + l * 4),
                    (__attribute__((address_space(3))) uint*)(lb + w * 512 + i * 256),
                    16, 0, 0);
            }
        }
#pragma unroll
        for (int i = 0; i < 8; ++i) {
            int p = i & 1, q = p ^ 1;

            short8 A[4];
#pragma unroll
            for (int kt = 0; kt < 4; ++kt)
                A[kt] = *(const short8*)&h2[p][rr][kt * 32 + kg];

            // 12 MFMA, 6 accumulators (3 gates x 2 K-halves), chain depth 2
            f32x4 aA[3], aB[3];
#pragma unroll
            for (int g3 = 0; g3 < 3; ++g3) {
                aA[g3] = (f32x4){0.f, 0.f, 0.f, 0.f};
                aB[g3] = (f32x4){0.f, 0.f, 0.f, 0.f};
            }
#pragma unroll
            for (int kt = 0; kt < 2; ++kt) {
#pragma unroll
                for (int g3 = 0; g3 < 3; ++g3) {
                    aA[g3] = mfma_bf16(A[kt], Bf[g3][kt], aA[g3]);
                    aB[g3] = mfma_bf16(A[kt + 2], Bf[g3][kt + 2], aB[g3]);
                }
            }

            if (l < 16) {
                const float4 cg = *(const float4*)&gxs[c & 1][i][j0][0];
                float ghr = aA[0][0] + aA[0][1] + aB[0][0] + aB[0][1];  // hi+lo, both K-halves
                float ghz = aA[1][0] + aA[1][1] + aB[1][0] + aB[1][1];
                float ghn = aA[2][0] + aA[2][1] + aB[2][0] + aB[2][1];
                float rg = sigf(cg.x + ghr);
                float zg = sigf(cg.y + ghz);
                float nn = cg.z + rg * (ghn + bhn);
                float th = 2.f * sigf(2.f * nn) - 1.f;
                hp = (1.f - zg) * th + zg * hp;
                unsigned short hh, ll;
                split_rne(hp, hh, ll);
                h2[q][0][j0] = hh;
                h2[q][1][j0] = ll;
            }
            __builtin_amdgcn_sched_barrier(0);
            if (i == 7) {
                asm volatile("s_waitcnt vmcnt(0) lgkmcnt(0)" ::: "memory");
            } else {
                asm volatile("s_waitcnt lgkmcnt(0)" ::: "memory");
            }
            __builtin_amdgcn_s_barrier();
            __builtin_amdgcn_sched_barrier(0);
        }
    }
    __builtin_amdgcn_s_setprio(0);

    // ---- per-batch tail: wait combine, then MLP + LN ----
    if (l < 16) hfl[j0] = hp;
    if (t == 0) {
        while (atomicAdd(&flags[1], 0) < 8) __builtin_amdgcn_s_sleep(8);
    }
    __syncthreads();
    if (t < H) gl2[t] = atomicAdd(&gs[b * H + t], 0.f) + hfl[t];
    __syncthreads();

    float h1 = 0.f;
    if (t < 256) {
        h1 = b1[t];
        for (int i = 0; i < H; ++i) h1 += gl2[i] * W1[i * TWO_H + t];
    }
    float s1 = (t < 256) ? h1 : 0.f;
    float s2 = (t < 256) ? h1 * h1 : 0.f;
#pragma unroll
    for (int off = 32; off; off >>= 1) {
        s1 += __shfl_xor(s1, off);
        s2 += __shfl_xor(s2, off);
    }
    if (l == 0) {
        red[w * 2] = s1;
        red[w * 2 + 1] = s2;
    }
    __syncthreads();
    {
        float S1 = red[0] + red[2] + red[4] + red[6] + red[8] + red[10] + red[12] + red[14];
        float S2 = red[1] + red[3] + red[5] + red[7] + red[9] + red[11] + red[13] + red[15];
        float mu = S1 / 256.f;
        float var = S2 / 256.f - mu * mu;
        float is = rsqrtf(var + 1e-5f);
        if (t < 256) {
            float y = (h1 - mu) * is * lng[t] + lnb[t];
            yl[t] = fmaxf(y, 0.f);
        }
    }
    __syncthreads();
    if (t < H) {
        float a = b2v[t];
        for (int i = 0; i < TWO_H; ++i) a += yl[i] * W2[i * H + t];
        out[b * H + t] = a;
    }
    __syncthreads();
    if (t == 0) {
        __threadfence();
        atomicAdd(&flags[16], 1);  // release burn blocks (cold cacheline)
    }
}

extern "C" void kernel_launch(void* const* d_in, const int* in_sizes, int n_in,
                              void* d_out, int out_size, void* d_ws, size_t ws_size,
                              hipStream_t stream) {
    const float* nodes = (const float*)d_in[0];
    const float* temporal = (const float*)d_in[1];
    const float* relW = (const float*)d_in[2];
    const float* relb = (const float*)d_in[3];
    const float* gru_Wih = (const float*)d_in[4];
    const float* gru_Whh = (const float*)d_in[5];
    const float* gru_bih = (const float*)d_in[6];
    const float* gru_bhh = (const float*)d_in[7];
    const float* mlp_W1 = (const float*)d_in[8];
    const float* mlp_b1 = (const float*)d_in[9];
    const float* ln_g = (const float*)d_in[10];
    const float* ln_b = (const float*)d_in[11];
    const float* mlp_W2 = (const float*)d_in[12];
    const float* mlp_b2 = (const float*)d_in[13];
    const int* src = (const int*)d_in[14];
    const int* rel = (const int*)d_in[15];
    const int* dst = (const int*)d_in[16];
    float* out = (float*)d_out;

    int E = in_sizes[14];
    int N = in_sizes[0] / 256;

    // ws layout (float units): gs(256) | cntg(8) | flags(24 ints) | Sg(4096) | csd | gxT2
    float* ws = (float*)d_ws;
    float* gs = ws;                     // 0..255
    float* cntg = ws + 256;             // 256..263
    int* flags = (int*)(ws + 264);      // 264..287 (flags[16] = done, separate cacheline)
    float* Sg = ws + 288;               // 288..4383
    uint* csd = (uint*)(ws + 4384);     // 8*N (hist only)

    size_t need_hist = (size_t)(4384 + 8 * N + 65536) * 4;
    int hist = ws_size >= need_hist ? 1 : 0;

    float* gxT2 = hist ? (ws + 4384 + 8 * N) : (ws + 4384);
    size_t zbytes = hist ? (size_t)(4384 + 8 * N) * 4 : (size_t)4384 * 4;
    hipMemsetAsync(d_ws, 0, zbytes, stream);

    int naccum, nreal, nblk;
    if (hist) {
        naccum = NACC;
        nreal = 10 + NGX + NACC;   // 266
        nblk = NTOT;               // + 246 burn blocks, all co-resident
    } else {
        int epb = (E + 511) / 512;
        k_edges_fb<<<512, 256, 0, stream>>>(nodes, src, rel, dst, Sg, cntg, E, epb);
        naccum = 0;
        nreal = 10 + NGX;
        nblk = NTOT;
    }
    int nch = (N + NACC - 1) / NACC;

    k_fused<<<nblk, 512, 0, stream>>>(nodes, src, rel, dst, temporal, gru_Wih, gru_bih,
                                      csd, Sg, cntg, relW, relb, gs, flags,
                                      1.f / (float)E, gxT2, gru_Whh, gru_bhh, mlp_W1,
                                      mlp_b1, ln_g, ln_b, mlp_W2, mlp_b2, out,
                                      N, E, nch, naccum, hist, nreal);
}

// Round 18
// 85.870 us; speedup vs baseline: 1.4645x; 1.4645x over previous
//
#include <hip/hip_runtime.h>
#include <hip/hip_bf16.h>
#include <math.h>

#define H 128
#define TT 64
#define TWO_H 256
#define NGX 128
#define NACC 128

typedef short short8 __attribute__((ext_vector_type(8)));
typedef __bf16 bf16x8_t __attribute__((ext_vector_type(8)));
typedef float f32x4 __attribute__((ext_vector_type(4)));
typedef unsigned int uint;

__device__ inline unsigned short bf_rne(float f) {
    __hip_bfloat16 b = __float2bfloat16(f);
    return __builtin_bit_cast(unsigned short, b);
}
__device__ inline void split_rne(float f, unsigned short& hi, unsigned short& lo) {
    __hip_bfloat16 h1 = __float2bfloat16(f);
    float fh = __bfloat162float(h1);
    hi = __builtin_bit_cast(unsigned short, h1);
    lo = bf_rne(f - fh);
}
__device__ inline f32x4 mfma_bf16(short8 a, short8 b, f32x4 c) {
    return __builtin_amdgcn_mfma_f32_16x16x32_bf16(
        __builtin_bit_cast(bf16x8_t, a), __builtin_bit_cast(bf16x8_t, b), c, 0, 0, 0);
}
__device__ inline float sigf(float x) { return 1.f / (1.f + __expf(-x)); }

// ---------- fallback (only if workspace too small for histogram path) ----------
__global__ void k_edges_fb(const float* __restrict__ nodes, const int* __restrict__ src,
                           const int* __restrict__ rel, const int* __restrict__ dst,
                           float* __restrict__ Sg, float* __restrict__ cntg, int E, int epb) {
    __shared__ float Sl[8 * 512];
    __shared__ float cnt[8];
    int t = threadIdx.x;
    for (int i = t; i < 8 * 512; i += 256) Sl[i] = 0.f;
    if (t < 8) cnt[t] = 0.f;
    __syncthreads();
    int e0 = blockIdx.x * epb, e1 = min(E, e0 + epb);
    int tS = ((t >> 7) << 8) + (t & 127);
    for (int e = e0; e < e1; ++e) {
        int r = rel[e];
        float vs = nodes[(size_t)src[e] * 256 + t];
        float vd = nodes[(size_t)dst[e] * 256 + t];
        Sl[r * 512 + tS] += vs;
        Sl[r * 512 + tS + 128] += vd;
        if (t == 0) cnt[r] += 1.f;
    }
    __syncthreads();
    for (int i = t; i < 8 * 512; i += 256) atomicAdd(&Sg[i], Sl[i]);
    if (t < 8) atomicAdd(&cntg[t], cnt[t]);
}

// ===== single fused kernel (512 threads): GRU(b0)|GRU(b1) | combine | gx(+count) | accum =====
// flags: [0]=accum done, [1]=combine done, [2]=count done, [5]=gx done
__launch_bounds__(512, 1)
__global__ void k_fused(const float* __restrict__ nodes, const int* __restrict__ src,
                        const int* __restrict__ rel, const int* __restrict__ dst,
                        const float* __restrict__ x, const float* __restrict__ Wih,
                        const float* __restrict__ bih, uint* __restrict__ csd,
                        float* __restrict__ Sg, float* __restrict__ cntg,
                        const float* __restrict__ relW, const float* __restrict__ relb,
                        float* __restrict__ gs, int* __restrict__ flags, float invE,
                        float* __restrict__ gxT2, const float* __restrict__ Whh,
                        const float* __restrict__ bhh, const float* __restrict__ W1,
                        const float* __restrict__ b1, const float* __restrict__ lng,
                        const float* __restrict__ lnb, const float* __restrict__ W2,
                        const float* __restrict__ b2v, float* __restrict__ out,
                        int N, int E, int nch, int naccum, int hist) {
    int t = threadIdx.x;
    int bid = blockIdx.x;

    if (bid >= 10 && bid < 10 + NGX) {
        // ================= gx block: gx FIRST (signal), then count slice =================
        int idx = bid - 10;
        __shared__ float xs[H];
        int tt = idx >> 1, bb = idx & 1;
        if (t < H) xs[t] = x[(bb * TT + tt) * H + t];
        __syncthreads();
        for (int o = t; o < 384; o += 512) {
            const float4* wp = (const float4*)(Wih + o * H);
            float acc = 0.f;
#pragma unroll
            for (int i = 0; i < 32; ++i) {
                float4 w = wp[i];
                acc += w.x * xs[4 * i] + w.y * xs[4 * i + 1] + w.z * xs[4 * i + 2] +
                       w.w * xs[4 * i + 3];
            }
            float bias = bih[o] + (o < TWO_H ? bhh[o] : 0.f);  // bhh_n not foldable
            int g = o >> 7, j = o & 127;
            gxT2[((size_t)(bb * TT + tt) * 128 + j) * 4 + g] = acc + bias;  // [b][t][j][4]
        }
        __syncthreads();
        if (t == 0) {
            __threadfence();
            atomicAdd(&flags[5], 1);  // gx ready
        }
        if (hist) {
            int per = (E + NGX - 1) / NGX;
            int e0 = idx * per, e1 = min(E, e0 + per);
            for (int e = e0 + t; e < e1; e += 512) {
                int r = rel[e];
                atomicAdd(&csd[(size_t)src[e] * 8 + r], 1u);
                atomicAdd(&csd[(size_t)dst[e] * 8 + r], 65536u);
            }
            __syncthreads();
            if (t == 0) {
                __threadfence();
                atomicAdd(&flags[2], 1);
            }
        }
        return;
    }

    if (bid >= 10 + NGX) {
        // ================= accum: stream nodes once, weighted by counts =================
        int ai = bid - 10 - NGX;
        if (t == 0) {
            while (atomicAdd(&flags[2], 0) < NGX) __builtin_amdgcn_s_sleep(8);
            __threadfence();
        }
        __syncthreads();
        if (t < 256) {
            int n0 = ai * nch, n1 = min(N, n0 + nch);
            float sA[8] = {0, 0, 0, 0, 0, 0, 0, 0};
            float sB[8] = {0, 0, 0, 0, 0, 0, 0, 0};
            float caR[8] = {0, 0, 0, 0, 0, 0, 0, 0};
            int n = n0;
            for (; n + 4 <= n1; n += 4) {
                float v0 = nodes[(size_t)(n + 0) * 256 + t];
                float v1 = nodes[(size_t)(n + 1) * 256 + t];
                float v2 = nodes[(size_t)(n + 2) * 256 + t];
                float v3 = nodes[(size_t)(n + 3) * 256 + t];
                uint4 a0 = *(const uint4*)(csd + (size_t)(n + 0) * 8);
                uint4 a1 = *(const uint4*)(csd + (size_t)(n + 0) * 8 + 4);
                uint4 b0 = *(const uint4*)(csd + (size_t)(n + 1) * 8);
                uint4 b1u = *(const uint4*)(csd + (size_t)(n + 1) * 8 + 4);
                uint4 c0 = *(const uint4*)(csd + (size_t)(n + 2) * 8);
                uint4 c1 = *(const uint4*)(csd + (size_t)(n + 2) * 8 + 4);
                uint4 d0 = *(const uint4*)(csd + (size_t)(n + 3) * 8);
                uint4 d1 = *(const uint4*)(csd + (size_t)(n + 3) * 8 + 4);
                uint ca[8] = {a0.x, a0.y, a0.z, a0.w, a1.x, a1.y, a1.z, a1.w};
                uint cb[8] = {b0.x, b0.y, b0.z, b0.w, b1u.x, b1u.y, b1u.z, b1u.w};
                uint cc[8] = {c0.x, c0.y, c0.z, c0.w, c1.x, c1.y, c1.z, c1.w};
                uint cd2[8] = {d0.x, d0.y, d0.z, d0.w, d1.x, d1.y, d1.z, d1.w};
#pragma unroll
                for (int r = 0; r < 8; ++r) {
                    float fs0 = (float)(ca[r] & 0xffffu), fd0 = (float)(ca[r] >> 16);
                    float fs1 = (float)(cb[r] & 0xffffu), fd1 = (float)(cb[r] >> 16);
                    float fs2 = (float)(cc[r] & 0xffffu), fd2 = (float)(cc[r] >> 16);
                    float fs3 = (float)(cd2[r] & 0xffffu), fd3 = (float)(cd2[r] >> 16);
                    sA[r] += fs0 * v0 + fs1 * v1 + fs2 * v2 + fs3 * v3;
                    sB[r] += fd0 * v0 + fd1 * v1 + fd2 * v2 + fd3 * v3;
                    caR[r] += fs0 + fs1 + fs2 + fs3;
                }
            }
            for (; n < n1; ++n) {
                float v = nodes[(size_t)n * 256 + t];
                const uint* cp = csd + (size_t)n * 8;
                uint4 c0 = *(const uint4*)cp;
                uint4 c1 = *(const uint4*)(cp + 4);
                uint cc[8] = {c0.x, c0.y, c0.z, c0.w, c1.x, c1.y, c1.z, c1.w};
#pragma unroll
                for (int r = 0; r < 8; ++r) {
                    float fs = (float)(cc[r] & 0xffffu);
                    float fd = (float)(cc[r] >> 16);
                    sA[r] += fs * v;
                    sB[r] += fd * v;
                    caR[r] += fs;
                }
            }
            int b = t >> 7, h = t & 127;
#pragma unroll
            for (int r = 0; r < 8; ++r) {
                atomicAdd(&Sg[r * 512 + b * 256 + h], sA[r]);
                atomicAdd(&Sg[r * 512 + b * 256 + 128 + h], sB[r]);
            }
            if (t == 0) {
#pragma unroll
                for (int r = 0; r < 8; ++r) atomicAdd(&cntg[r], caR[r]);
            }
        }
        __syncthreads();
        if (t == 0) {
            __threadfence();
            atomicAdd(&flags[0], 1);
        }
        return;
    }

    if (bid >= 2) {
        // ================= combine r: gs += (S_r @ W_r + cnt_r*b_r)/E =================
        int r = bid - 2;
        __shared__ float Sc[512];
        if (t == 0) {
            while (atomicAdd(&flags[0], 0) < naccum) __builtin_amdgcn_s_sleep(8);
        }
        __syncthreads();
        for (int i = t; i < 512; i += 512) Sc[i] = atomicAdd(&Sg[r * 512 + i], 0.f);
        __syncthreads();
        if (t < 256) {
            int b = t >> 7, h = t & 127;
            const float* Wr = relW + (size_t)r * TWO_H * H;
            float acc = 0.f;
#pragma unroll 8
            for (int c = 0; c < TWO_H; ++c) acc += Sc[b * 256 + c] * Wr[c * H + h];
            acc += atomicAdd(&cntg[r], 0.f) * relb[r * H + h];
            atomicAdd(&gs[t], acc * invE);
        }
        __syncthreads();
        if (t == 0) {
            __threadfence();
            atomicAdd(&flags[1], 1);
        }
        return;
    }

    // ============ blocks 0,1: per-batch GRU, 8 waves, LDS-staged gx ============
    int b = bid;  // batch index
    // h rows: 0=hi 1=lo 2=zero; double-buffered; pad 144 -> max 2-way bank alias (free)
    __shared__ __align__(16) unsigned short h2[2][3][144];
    __shared__ __align__(16) float gxs[2][8][128][4];  // 2 x 16KB staged gx chunks
    __shared__ float hfl[H];
    __shared__ float gl2[H];
    __shared__ float yl[TWO_H];
    __shared__ float red[16];

    int w = t >> 6, l = t & 63;  // 8 waves

    for (int i = t; i < 2 * 3 * 144; i += 512) ((unsigned short*)h2)[i] = 0;

    // B fragments: wave w owns j in [16w, 16w+16) for all 3 gates: tile g -> row-tile g*8+w
    short8 Bf[3][4];
#pragma unroll
    for (int g3 = 0; g3 < 3; ++g3) {
        int row = (g3 * 8 + w) * 16 + (l & 15);
#pragma unroll
        for (int kt = 0; kt < 4; ++kt) {
            const float4* wp = (const float4*)(Whh + row * H + kt * 32 + (l >> 4) * 8);
            float4 w0 = wp[0], w1 = wp[1];
            float ww[8] = {w0.x, w0.y, w0.z, w0.w, w1.x, w1.y, w1.z, w1.w};
            short8 v8;
#pragma unroll
            for (int e = 0; e < 8; ++e) v8[e] = (short)bf_rne(ww[e]);
            Bf[g3][kt] = v8;
        }
    }

    int al = l & 15;
    int rr = al < 2 ? al : 2;  // A-row: 0=hi 1=lo, >=2 zero broadcast
    int kg = (l >> 4) * 8;

    // gate lanes l<16: ONE unit each, j = w*16 + l
    float hp = 0.f;
    float bhn = 0.f;
    int j0 = w * 16 + l;
    if (l < 16) bhn = bhh[TWO_H + j0];

    const float* gxb = gxT2 + (size_t)b * TT * 512;  // this batch's gx [64][128][4]

    // wait once for ALL gx producers, then stage chunk 0 (16KB, 2 loads/wave)
    if (t == 0) {
        while (atomicAdd(&flags[5], 0) < NGX) __builtin_amdgcn_s_sleep(2);
        __threadfence();
    }
    __syncthreads();
    {
        float* lb = &gxs[0][0][0][0];
#pragma unroll
        for (int i = 0; i < 2; ++i) {
            __builtin_amdgcn_global_load_lds(
                (const __attribute__((address_space(1))) uint*)(gxb + w * 512 + i * 256 + l * 4),
                (__attribute__((address_space(3))) uint*)(lb + w * 512 + i * 256),
                16, 0, 0);
        }
    }
    __syncthreads();  // drains vmcnt(0): chunk 0 staged; h2 zeros visible

    __builtin_amdgcn_s_setprio(1);
    for (int c = 0; c < 8; ++c) {
        if (c < 7) {
            float* lb = &gxs[(c + 1) & 1][0][0][0];
            const float* sb = gxb + (size_t)(c + 1) * 4096;
#pragma unroll
            for (int i = 0; i < 2; ++i) {
                __builtin_amdgcn_global_load_lds(
                    (const __attribute__((address_space(1))) uint*)(sb + w * 512 + i * 256 + l * 4),
                    (__attribute__((address_space(3))) uint*)(lb + w * 512 + i * 256),
                    16, 0, 0);
            }
        }
#pragma unroll
        for (int i = 0; i < 8; ++i) {
            int p = i & 1, q = p ^ 1;

            short8 A[4];
#pragma unroll
            for (int kt = 0; kt < 4; ++kt)
                A[kt] = *(const short8*)&h2[p][rr][kt * 32 + kg];

            // 12 MFMA, 6 accumulators (3 gates x 2 K-halves), chain depth 2
            f32x4 aA[3], aB[3];
#pragma unroll
            for (int g3 = 0; g3 < 3; ++g3) {
                aA[g3] = (f32x4){0.f, 0.f, 0.f, 0.f};
                aB[g3] = (f32x4){0.f, 0.f, 0.f, 0.f};
            }
#pragma unroll
            for (int kt = 0; kt < 2; ++kt) {
#pragma unroll
                for (int g3 = 0; g3 < 3; ++g3) {
                    aA[g3] = mfma_bf16(A[kt], Bf[g3][kt], aA[g3]);
                    aB[g3] = mfma_bf16(A[kt + 2], Bf[g3][kt + 2], aB[g3]);
                }
            }

            if (l < 16) {
                const float4 cg = *(const float4*)&gxs[c & 1][i][j0][0];
                float ghr = aA[0][0] + aA[0][1] + aB[0][0] + aB[0][1];  // hi+lo, both K-halves
                float ghz = aA[1][0] + aA[1][1] + aB[1][0] + aB[1][1];
                float ghn = aA[2][0] + aA[2][1] + aB[2][0] + aB[2][1];
                float rg = sigf(cg.x + ghr);
                float zg = sigf(cg.y + ghz);
                float nn = cg.z + rg * (ghn + bhn);
                float th = 2.f * sigf(2.f * nn) - 1.f;
                hp = (1.f - zg) * th + zg * hp;
                unsigned short hh, ll;
                split_rne(hp, hh, ll);
                h2[q][0][j0] = hh;
                h2[q][1][j0] = ll;
            }
            __builtin_amdgcn_sched_barrier(0);
            if (i == 7) {
                asm volatile("s_waitcnt vmcnt(0) lgkmcnt(0)" ::: "memory");
            } else {
                asm volatile("s_waitcnt lgkmcnt(0)" ::: "memory");
            }
            __builtin_amdgcn_s_barrier();
            __builtin_amdgcn_sched_barrier(0);
        }
    }
    __builtin_amdgcn_s_setprio(0);

    // ---- per-batch tail: wait combine, then MLP + LN ----
    if (l < 16) hfl[j0] = hp;
    if (t == 0) {
        while (atomicAdd(&flags[1], 0) < 8) __builtin_amdgcn_s_sleep(8);
    }
    __syncthreads();
    if (t < H) gl2[t] = atomicAdd(&gs[b * H + t], 0.f) + hfl[t];
    __syncthreads();

    float h1 = 0.f;
    if (t < 256) {
        h1 = b1[t];
        for (int i = 0; i < H; ++i) h1 += gl2[i] * W1[i * TWO_H + t];
    }
    float s1 = (t < 256) ? h1 : 0.f;
    float s2 = (t < 256) ? h1 * h1 : 0.f;
#pragma unroll
    for (int off = 32; off; off >>= 1) {
        s1 += __shfl_xor(s1, off);
        s2 += __shfl_xor(s2, off);
    }
    if (l == 0) {
        red[w * 2] = s1;
        red[w * 2 + 1] = s2;
    }
    __syncthreads();
    {
        float S1 = red[0] + red[2] + red[4] + red[6] + red[8] + red[10] + red[12] + red[14];
        float S2 = red[1] + red[3] + red[5] + red[7] + red[9] + red[11] + red[13] + red[15];
        float mu = S1 / 256.f;
        float var = S2 / 256.f - mu * mu;
        float is = rsqrtf(var + 1e-5f);
        if (t < 256) {
            float y = (h1 - mu) * is * lng[t] + lnb[t];
            yl[t] = fmaxf(y, 0.f);
        }
    }
    __syncthreads();
    if (t < H) {
        float a = b2v[t];
        for (int i = 0; i < TWO_H; ++i) a += yl[i] * W2[i * H + t];
        out[b * H + t] = a;
    }
}

extern "C" void kernel_launch(void* const* d_in, const int* in_sizes, int n_in,
                              void* d_out, int out_size, void* d_ws, size_t ws_size,
                              hipStream_t stream) {
    const float* nodes = (const float*)d_in[0];
    const float* temporal = (const float*)d_in[1];
    const float* relW = (const float*)d_in[2];
    const float* relb = (const float*)d_in[3];
    const float* gru_Wih = (const float*)d_in[4];
    const float* gru_Whh = (const float*)d_in[5];
    const float* gru_bih = (const float*)d_in[6];
    const float* gru_bhh = (const float*)d_in[7];
    const float* mlp_W1 = (const float*)d_in[8];
    const float* mlp_b1 = (const float*)d_in[9];
    const float* ln_g = (const float*)d_in[10];
    const float* ln_b = (const float*)d_in[11];
    const float* mlp_W2 = (const float*)d_in[12];
    const float* mlp_b2 = (const float*)d_in[13];
    const int* src = (const int*)d_in[14];
    const int* rel = (const int*)d_in[15];
    const int* dst = (const int*)d_in[16];
    float* out = (float*)d_out;

    int E = in_sizes[14];
    int N = in_sizes[0] / 256;

    // ws layout (float units): gs(256) | cntg(8) | flags(24 ints) | Sg(4096) | csd | gxT2
    float* ws = (float*)d_ws;
    float* gs = ws;                     // 0..255
    float* cntg = ws + 256;             // 256..263
    int* flags = (int*)(ws + 264);      // 264..287
    float* Sg = ws + 288;               // 288..4383
    uint* csd = (uint*)(ws + 4384);     // 8*N (hist only)

    size_t need_hist = (size_t)(4384 + 8 * N + 65536) * 4;
    int hist = ws_size >= need_hist ? 1 : 0;

    float* gxT2 = hist ? (ws + 4384 + 8 * N) : (ws + 4384);
    size_t zbytes = hist ? (size_t)(4384 + 8 * N) * 4 : (size_t)4384 * 4;
    hipMemsetAsync(d_ws, 0, zbytes, stream);

    int naccum, nblk;
    if (hist) {
        naccum = NACC;
        nblk = 10 + NGX + NACC;
    } else {
        int epb = (E + 511) / 512;
        k_edges_fb<<<512, 256, 0, stream>>>(nodes, src, rel, dst, Sg, cntg, E, epb);
        naccum = 0;
        nblk = 10 + NGX;
    }
    int nch = (N + NACC - 1) / NACC;

    k_fused<<<nblk, 512, 0, stream>>>(nodes, src, rel, dst, temporal, gru_Wih, gru_bih,
                                      csd, Sg, cntg, relW, relb, gs, flags,
                                      1.f / (float)E, gxT2, gru_Whh, gru_bhh, mlp_W1,
                                      mlp_b1, ln_g, ln_b, mlp_W2, mlp_b2, out,
                                      N, E, nch, naccum, hist);
}